// Round 16
// baseline (170.060 us; speedup 1.0000x reference)
//
#include <hip/hip_runtime.h>

typedef __bf16 bf16x8 __attribute__((ext_vector_type(8)));
typedef __bf16 bf16x4 __attribute__((ext_vector_type(4)));
typedef float f32x4 __attribute__((ext_vector_type(4)));
typedef short s16x4 __attribute__((ext_vector_type(4)));

#define NB 4
#define NC 64
#define NN 4096
#define SPLIT 8   // key-dim splits for flash

// sc folded into Q at qkv time: softmax uses exp2(q.k * 0.125 * log2(e))
#define QSCALE (0.125f * 1.44269504088896340736f)

#if __has_builtin(__builtin_amdgcn_exp2f)
#define EXP2(x) __builtin_amdgcn_exp2f(x)   // raw v_exp_f32; inputs are O(1)
#else
#define EXP2(x) exp2f(x)
#endif

// ---------------------------------------------------------------------------
// Kernel 1: QKV projection via MFMA, LDS-free (R14-exact) + counter zeroing.
// grid(32, B, 3): z = tensor; block = 128 n; wave = 32 n.  384 blocks.
// ---------------------------------------------------------------------------
__global__ __launch_bounds__(256) void qkv_kernel(
    const float* __restrict__ x, const float* __restrict__ wqkv,
    const float* __restrict__ bqkv,
    __bf16* __restrict__ Qg, __bf16* __restrict__ Kg, __bf16* __restrict__ Vg,
    int* __restrict__ cnt)
{
  const int tid = threadIdx.x;
  const int wave = tid >> 6;
  const int lane = tid & 63;
  const int quad = lane >> 4;
  const int l16 = lane & 15;
  const int b = blockIdx.y;
  const int tsel = blockIdx.z;                 // 0=q, 1=k, 2=v
  const int n0 = blockIdx.x * 128 + wave * 32; // wave's 32 n
  const float wscale = (tsel == 0) ? QSCALE : 1.0f;

  // zero the last-block counters (visible to flash via dispatch boundary)
  if (blockIdx.x == 0 && blockIdx.y == 0 && blockIdx.z == 0 && tid < NB * 32)
    cnt[tid] = 0;

  // preload W^T B-frags: [ot][ch]; oc = ot*16+l16, c = ch*32+quad*8+j
  bf16x8 wf[4][2];
#pragma unroll
  for (int ot = 0; ot < 4; ot++) {
#pragma unroll
    for (int ch = 0; ch < 2; ch++) {
      const float* wp =
          wqkv + (size_t)(tsel * 64 + ot * 16 + l16) * 64 + ch * 32 + quad * 8;
      const float4 w0 = *(const float4*)wp;
      const float4 w1 = *(const float4*)(wp + 4);
      bf16x8 f;
      f[0] = (__bf16)(w0.x * wscale); f[1] = (__bf16)(w0.y * wscale);
      f[2] = (__bf16)(w0.z * wscale); f[3] = (__bf16)(w0.w * wscale);
      f[4] = (__bf16)(w1.x * wscale); f[5] = (__bf16)(w1.y * wscale);
      f[6] = (__bf16)(w1.z * wscale); f[7] = (__bf16)(w1.w * wscale);
      wf[ot][ch] = f;
    }
  }
  float bv[4];
#pragma unroll
  for (int ot = 0; ot < 4; ot++)
    bv[ot] = bqkv[tsel * 64 + ot * 16 + l16] * wscale;

#pragma unroll
  for (int nt = 0; nt < 2; nt++) {
    const int nb = n0 + nt * 16 + l16;

    bf16x8 xf[2];
#pragma unroll
    for (int ch = 0; ch < 2; ch++) {
      float v[8];
#pragma unroll
      for (int j = 0; j < 8; j++)
        v[j] = x[(size_t)(b * 64 + ch * 32 + quad * 8 + j) * NN + nb];
      bf16x8 f;
#pragma unroll
      for (int j = 0; j < 8; j++) f[j] = (__bf16)v[j];
      xf[ch] = f;
    }

#pragma unroll
    for (int ot = 0; ot < 4; ot++) {
      f32x4 acc = (f32x4){bv[ot], bv[ot], bv[ot], bv[ot]};
      acc = __builtin_amdgcn_mfma_f32_16x16x32_bf16(xf[0], wf[ot][0], acc, 0, 0, 0);
      acc = __builtin_amdgcn_mfma_f32_16x16x32_bf16(xf[1], wf[ot][1], acc, 0, 0, 0);

      if (tsel < 2) {
        __bf16* dst = (tsel == 0) ? Qg : Kg;
#pragma unroll
        for (int r = 0; r < 4; r++)
          dst[(size_t)(b * NN + n0 + nt * 16 + quad * 4 + r) * 64 + ot * 16 + l16] =
              (__bf16)acc[r];
      } else {
        bf16x4 pv;
#pragma unroll
        for (int r = 0; r < 4; r++) pv[r] = (__bf16)acc[r];
        *(bf16x4*)(Vg + (size_t)(b * 64 + ot * 16 + l16) * NN +
                   n0 + nt * 16 + quad * 4) = pv;
      }
    }
  }
}

// ---------------------------------------------------------------------------
// Kernel 2: flash attention (R14-exact core + fused proj epilogue) + LAST-
// BLOCK COMBINE: after storing proj-space partials, each block fences and
// atomically increments cnt[b*32+xblk]; the 8th (last) block for that
// (b, 128-q range) re-fences and performs the combine (sum splits, 1/l,
// bias, residual) for those 128 n — dispatch-order-safe (nobody waits).
// grid(32, B, SPLIT), 256 thr = 4 waves; wave owns 32 q, block 128 q.
// ---------------------------------------------------------------------------
__global__ __launch_bounds__(256) void flash_kernel(
    const __bf16* __restrict__ Q, const __bf16* __restrict__ K,
    const __bf16* __restrict__ V, const float* __restrict__ wproj,
    const float* __restrict__ bproj, const float* __restrict__ x,
    __bf16* __restrict__ Opart, float* __restrict__ lpart,
    int* __restrict__ cnt, float* __restrict__ out)
{
  const int xblk = blockIdx.x;
  const int b = blockIdx.y;
  const int s = blockIdx.z;
  const int tid = threadIdx.x;
  const int wave = tid >> 6;
  const int lane = tid & 63;
  const int quad = lane >> 4;
  const int l16 = lane & 15;

  __shared__ __bf16 Kt[64 * 72];      // [key][c], padded
  __shared__ __bf16 Vt[64 * 72];      // [c][key], padded
  __shared__ int lastFlag;

  const int q0 = xblk * 128 + wave * 32;

  bf16x8 qf[2][2];
#pragma unroll
  for (int qt = 0; qt < 2; qt++) {
    const __bf16* qrow = Q + ((size_t)(b * NN + q0 + qt * 16 + l16)) * 64;
    qf[qt][0] = *(const bf16x8*)(qrow + quad * 8);
    qf[qt][1] = *(const bf16x8*)(qrow + 32 + quad * 8);
  }

  f32x4 acc[2][4];    // O^T acc: row c = ct*16+quad*4+r, col q = qt*16+l16
#pragma unroll
  for (int qt = 0; qt < 2; qt++)
#pragma unroll
    for (int ct = 0; ct < 4; ct++) acc[qt][ct] = (f32x4){0.f, 0.f, 0.f, 0.f};
  float l[2] = {0.f, 0.f};

  const int kbeg = s * (NN / SPLIT);
  const int kend = kbeg + (NN / SPLIT);
#pragma unroll 1
  for (int kt0 = kbeg; kt0 < kend; kt0 += 64) {
    __syncthreads();
#pragma unroll
    for (int it = 0; it < 2; it++) {
      const int chunk = tid + it * 256;          // 512 chunks of 8 bf16
      const int row = chunk >> 3, col8 = (chunk & 7) * 8;
      *(bf16x8*)(&Kt[row * 72 + col8]) =
          *(const bf16x8*)(K + ((size_t)(b * NN + kt0 + row)) * 64 + col8);
      *(bf16x8*)(&Vt[row * 72 + col8]) =
          *(const bf16x8*)(V + ((size_t)(b * 64 + row)) * NN + kt0 + col8);
    }
    __syncthreads();

    // ---- S^T = K Q^T, P packed into registers --------------------------
    s16x4 pk[4][2];
#pragma unroll
    for (int t = 0; t < 4; t++) {
      const bf16x8 kf0 = *(const bf16x8*)(&Kt[(t * 16 + l16) * 72 + quad * 8]);
      const bf16x8 kf1 = *(const bf16x8*)(&Kt[(t * 16 + l16) * 72 + 32 + quad * 8]);
#pragma unroll
      for (int qt = 0; qt < 2; qt++) {
        f32x4 z = (f32x4){0.f, 0.f, 0.f, 0.f};
        z = __builtin_amdgcn_mfma_f32_16x16x32_bf16(kf0, qf[qt][0], z, 0, 0, 0);
        z = __builtin_amdgcn_mfma_f32_16x16x32_bf16(kf1, qf[qt][1], z, 0, 0, 0);
        const float p0 = EXP2(z[0]), p1 = EXP2(z[1]);
        const float p2 = EXP2(z[2]), p3 = EXP2(z[3]);
        l[qt] += (p0 + p1) + (p2 + p3);
        bf16x4 pv;
        pv[0] = (__bf16)p0; pv[1] = (__bf16)p1;
        pv[2] = (__bf16)p2; pv[3] = (__bf16)p3;
        pk[t][qt] = __builtin_bit_cast(s16x4, pv);
      }
    }

    // ---- O^T += V^T P^T : K=16 MFMAs, P straight from registers --------
#pragma unroll
    for (int kg = 0; kg < 4; kg++) {
#pragma unroll
      for (int ct = 0; ct < 4; ct++) {
        const bf16x4 va =
            *(const bf16x4*)(&Vt[(ct * 16 + l16) * 72 + kg * 16 + quad * 4]);
        const s16x4 a = __builtin_bit_cast(s16x4, va);
        acc[0][ct] = __builtin_amdgcn_mfma_f32_16x16x16bf16_1k(
            a, pk[kg][0], acc[0][ct], 0, 0, 0);
        acc[1][ct] = __builtin_amdgcn_mfma_f32_16x16x16bf16_1k(
            a, pk[kg][1], acc[1][ct], 0, 0, 0);
      }
    }
  }

  // ---- epilogue 1: l reduction (2 shuffles per q-tile) ------------------
#pragma unroll
  for (int qt = 0; qt < 2; qt++) {
    float lr = l[qt];
    lr += __shfl_xor(lr, 16);
    lr += __shfl_xor(lr, 32);
    if (quad == 0)
      lpart[((size_t)(s * NB + b)) * NN + q0 + qt * 16 + l16] = lr;
  }

  // ---- epilogue 2: fused proj.  Po^T = Wp * O^T -------------------------
  s16x4 ob[2][4];
#pragma unroll
  for (int qt = 0; qt < 2; qt++)
#pragma unroll
    for (int ch = 0; ch < 4; ch++) {
      bf16x4 t;
#pragma unroll
      for (int r = 0; r < 4; r++) t[r] = (__bf16)acc[qt][ch][r];
      ob[qt][ch] = __builtin_bit_cast(s16x4, t);
    }

#pragma unroll
  for (int cot = 0; cot < 4; cot++) {
    f32x4 po[2];
    po[0] = (f32x4){0.f, 0.f, 0.f, 0.f};
    po[1] = (f32x4){0.f, 0.f, 0.f, 0.f};
#pragma unroll
    for (int ch = 0; ch < 4; ch++) {
      const float4 wv =
          *(const float4*)&wproj[(cot * 16 + l16) * 64 + ch * 16 + quad * 4];
      bf16x4 wb;
      wb[0] = (__bf16)wv.x; wb[1] = (__bf16)wv.y;
      wb[2] = (__bf16)wv.z; wb[3] = (__bf16)wv.w;
      const s16x4 a = __builtin_bit_cast(s16x4, wb);
      po[0] = __builtin_amdgcn_mfma_f32_16x16x16bf16_1k(a, ob[0][ch], po[0], 0, 0, 0);
      po[1] = __builtin_amdgcn_mfma_f32_16x16x16bf16_1k(a, ob[1][ch], po[1], 0, 0, 0);
    }
#pragma unroll
    for (int qt = 0; qt < 2; qt++)
#pragma unroll
      for (int r = 0; r < 4; r++)
        Opart[(((size_t)(s * NB + b)) * 64 + cot * 16 + quad * 4 + r) * NN +
              q0 + qt * 16 + l16] = (__bf16)po[qt][r];
  }

  // ---- last-block combine ----------------------------------------------
  __syncthreads();                       // all waves' stores issued
  if (tid == 0) {
    __threadfence();                     // flush partials device-wide
    lastFlag = (atomicAdd(&cnt[b * 32 + xblk], 1) == SPLIT - 1);
  }
  __syncthreads();
  if (!lastFlag) return;
  __threadfence();                       // acquire: discard stale lines

  float* linv = (float*)Kt;              // reuse LDS
  const int c = tid >> 2;
  const int n8o = (tid & 3) * 8;

#pragma unroll 1
  for (int pass = 0; pass < 4; pass++) {
    const int n0 = xblk * 128 + pass * 32;
    __syncthreads();
    if (tid < 32) {
      float lt = 0.f;
#pragma unroll
      for (int ss = 0; ss < SPLIT; ss++)
        lt += lpart[((size_t)(ss * NB + b)) * NN + n0 + tid];
      linv[tid] = 1.0f / lt;
    }
    __syncthreads();

    float o[8];
#pragma unroll
    for (int j = 0; j < 8; j++) o[j] = 0.f;
#pragma unroll
    for (int ss = 0; ss < SPLIT; ss++) {
      const bf16x8 v = *(const bf16x8*)(
          Opart + (((size_t)(ss * NB + b)) * 64 + c) * NN + n0 + n8o);
#pragma unroll
      for (int j = 0; j < 8; j++) o[j] += (float)v[j];
    }

    const float bb = bproj[c];
    const float4 li0 = *(const float4*)&linv[n8o];
    const float4 li1 = *(const float4*)&linv[n8o + 4];
    const size_t base = ((size_t)(b * 64 + c)) * NN + n0 + n8o;
    const float4 x0 = *(const float4*)&x[base];
    const float4 x1 = *(const float4*)&x[base + 4];
    float4 r0, r1;
    r0.x = o[0] * li0.x + bb + x0.x;  r0.y = o[1] * li0.y + bb + x0.y;
    r0.z = o[2] * li0.z + bb + x0.z;  r0.w = o[3] * li0.w + bb + x0.w;
    r1.x = o[4] * li1.x + bb + x1.x;  r1.y = o[5] * li1.y + bb + x1.y;
    r1.z = o[6] * li1.z + bb + x1.z;  r1.w = o[7] * li1.w + bb + x1.w;
    *(float4*)&out[base] = r0;
    *(float4*)&out[base + 4] = r1;
  }
}

extern "C" void kernel_launch(void* const* d_in, const int* in_sizes, int n_in,
                              void* d_out, int out_size, void* d_ws, size_t ws_size,
                              hipStream_t stream) {
  const float* x     = (const float*)d_in[0];
  const float* wqkv  = (const float*)d_in[1];
  const float* bqkv  = (const float*)d_in[2];
  const float* wproj = (const float*)d_in[3];
  const float* bproj = (const float*)d_in[4];
  float* out = (float*)d_out;

  // Workspace: Q[0,2M) K[2,4M) V[4,6M) Opart[6,22M) lpart[23,23.5M) cnt[24M)
  char* ws = (char*)d_ws;
  __bf16* Q     = (__bf16*)(ws);
  __bf16* K     = (__bf16*)(ws + (2u << 20));
  __bf16* V     = (__bf16*)(ws + (4u << 20));
  __bf16* Opart = (__bf16*)(ws + (6u << 20));   // [S,B,C,N] = 16 MiB
  float*  lpart = (float*)(ws + (23u << 20));   // SPLIT*B*N*4 = 512 KiB
  int*    cnt   = (int*)(ws + (24u << 20));     // NB*32 counters

  qkv_kernel<<<dim3(32, NB, 3), 256, 0, stream>>>(x, wqkv, bqkv, Q, K, V, cnt);
  flash_kernel<<<dim3(32, NB, SPLIT), 256, 0, stream>>>(
      Q, K, V, wproj, bproj, x, Opart, lpart, cnt, out);
}

// Round 17
// 115.464 us; speedup vs baseline: 1.4728x; 1.4728x over previous
//
#include <hip/hip_runtime.h>

typedef __bf16 bf16x8 __attribute__((ext_vector_type(8)));
typedef __bf16 bf16x4 __attribute__((ext_vector_type(4)));
typedef float f32x4 __attribute__((ext_vector_type(4)));
typedef short s16x4 __attribute__((ext_vector_type(4)));

#define NB 4
#define NC 64
#define NN 4096
#define SPLIT 8   // key-dim splits for flash

// sc folded into Q at qkv time: softmax uses exp2(q.k * 0.125 * log2(e))
#define QSCALE (0.125f * 1.44269504088896340736f)

#if __has_builtin(__builtin_amdgcn_exp2f)
#define EXP2(x) __builtin_amdgcn_exp2f(x)   // raw v_exp_f32; inputs are O(1)
#else
#define EXP2(x) exp2f(x)
#endif

// ---------------------------------------------------------------------------
// Kernel 1: QKV projection via MFMA, LDS-free, barrier-free (R14-exact).
// grid(32, B, 3): z = tensor; block = 128 n; wave = 32 n.  384 blocks.
// ---------------------------------------------------------------------------
__global__ __launch_bounds__(256) void qkv_kernel(
    const float* __restrict__ x, const float* __restrict__ wqkv,
    const float* __restrict__ bqkv,
    __bf16* __restrict__ Qg, __bf16* __restrict__ Kg, __bf16* __restrict__ Vg)
{
  const int tid = threadIdx.x;
  const int wave = tid >> 6;
  const int lane = tid & 63;
  const int quad = lane >> 4;
  const int l16 = lane & 15;
  const int b = blockIdx.y;
  const int tsel = blockIdx.z;                 // 0=q, 1=k, 2=v
  const int n0 = blockIdx.x * 128 + wave * 32; // wave's 32 n
  const float wscale = (tsel == 0) ? QSCALE : 1.0f;

  // preload W^T B-frags: [ot][ch]; oc = ot*16+l16, c = ch*32+quad*8+j
  bf16x8 wf[4][2];
#pragma unroll
  for (int ot = 0; ot < 4; ot++) {
#pragma unroll
    for (int ch = 0; ch < 2; ch++) {
      const float* wp =
          wqkv + (size_t)(tsel * 64 + ot * 16 + l16) * 64 + ch * 32 + quad * 8;
      const float4 w0 = *(const float4*)wp;
      const float4 w1 = *(const float4*)(wp + 4);
      bf16x8 f;
      f[0] = (__bf16)(w0.x * wscale); f[1] = (__bf16)(w0.y * wscale);
      f[2] = (__bf16)(w0.z * wscale); f[3] = (__bf16)(w0.w * wscale);
      f[4] = (__bf16)(w1.x * wscale); f[5] = (__bf16)(w1.y * wscale);
      f[6] = (__bf16)(w1.z * wscale); f[7] = (__bf16)(w1.w * wscale);
      wf[ot][ch] = f;
    }
  }
  float bv[4];
#pragma unroll
  for (int ot = 0; ot < 4; ot++)
    bv[ot] = bqkv[tsel * 64 + ot * 16 + l16] * wscale;

#pragma unroll
  for (int nt = 0; nt < 2; nt++) {
    const int nb = n0 + nt * 16 + l16;

    bf16x8 xf[2];
#pragma unroll
    for (int ch = 0; ch < 2; ch++) {
      float v[8];
#pragma unroll
      for (int j = 0; j < 8; j++)
        v[j] = x[(size_t)(b * 64 + ch * 32 + quad * 8 + j) * NN + nb];
      bf16x8 f;
#pragma unroll
      for (int j = 0; j < 8; j++) f[j] = (__bf16)v[j];
      xf[ch] = f;
    }

#pragma unroll
    for (int ot = 0; ot < 4; ot++) {
      f32x4 acc = (f32x4){bv[ot], bv[ot], bv[ot], bv[ot]};
      acc = __builtin_amdgcn_mfma_f32_16x16x32_bf16(xf[0], wf[ot][0], acc, 0, 0, 0);
      acc = __builtin_amdgcn_mfma_f32_16x16x32_bf16(xf[1], wf[ot][1], acc, 0, 0, 0);

      if (tsel < 2) {
        __bf16* dst = (tsel == 0) ? Qg : Kg;
#pragma unroll
        for (int r = 0; r < 4; r++)
          dst[(size_t)(b * NN + n0 + nt * 16 + quad * 4 + r) * 64 + ot * 16 + l16] =
              (__bf16)acc[r];
      } else {
        bf16x4 pv;
#pragma unroll
        for (int r = 0; r < 4; r++) pv[r] = (__bf16)acc[r];
        *(bf16x4*)(Vg + (size_t)(b * 64 + ot * 16 + l16) * NN +
                   n0 + nt * 16 + quad * 4) = pv;
      }
    }
  }
}

// ---------------------------------------------------------------------------
// Kernel 2: flash attention, split-K, max-free softmax, fused proj epilogue.
// R14-exact per-wave structure; NEW: 512 threads = 8 waves per block, so one
// staged Kt/Vt copy serves 256 queries (vs 128) -> staged copies per CU and
// K/V global re-reads both halve; staging is 1 b128 store/thread/tile.
// grid(16, B, SPLIT) = 512 blocks; 2 blocks/CU x 8 waves = 16 waves/CU.
// Opart:[S,B,C,N] bf16 (unnorm, proj-space), lpart:[S,B,N].
// ---------------------------------------------------------------------------
__global__ __launch_bounds__(512) void flash_kernel(
    const __bf16* __restrict__ Q, const __bf16* __restrict__ K,
    const __bf16* __restrict__ V, const float* __restrict__ wproj,
    __bf16* __restrict__ Opart, float* __restrict__ lpart)
{
  const int b = blockIdx.y;
  const int s = blockIdx.z;
  const int tid = threadIdx.x;
  const int wave = tid >> 6;
  const int lane = tid & 63;
  const int quad = lane >> 4;
  const int l16 = lane & 15;

  __shared__ __bf16 Kt[64 * 72];      // [key][c], padded
  __shared__ __bf16 Vt[64 * 72];      // [c][key], padded

  const int q0 = blockIdx.x * 256 + wave * 32;

  bf16x8 qf[2][2];
#pragma unroll
  for (int qt = 0; qt < 2; qt++) {
    const __bf16* qrow = Q + ((size_t)(b * NN + q0 + qt * 16 + l16)) * 64;
    qf[qt][0] = *(const bf16x8*)(qrow + quad * 8);
    qf[qt][1] = *(const bf16x8*)(qrow + 32 + quad * 8);
  }

  f32x4 acc[2][4];    // O^T acc: row c = ct*16+quad*4+r, col q = qt*16+l16
#pragma unroll
  for (int qt = 0; qt < 2; qt++)
#pragma unroll
    for (int ct = 0; ct < 4; ct++) acc[qt][ct] = (f32x4){0.f, 0.f, 0.f, 0.f};
  float l[2] = {0.f, 0.f};

  const int kbeg = s * (NN / SPLIT);
  const int kend = kbeg + (NN / SPLIT);
#pragma unroll 1
  for (int kt0 = kbeg; kt0 < kend; kt0 += 64) {
    __syncthreads();
    {
      const int chunk = tid;                     // 512 chunks of 8 bf16
      const int row = chunk >> 3, col8 = (chunk & 7) * 8;
      *(bf16x8*)(&Kt[row * 72 + col8]) =
          *(const bf16x8*)(K + ((size_t)(b * NN + kt0 + row)) * 64 + col8);
      *(bf16x8*)(&Vt[row * 72 + col8]) =
          *(const bf16x8*)(V + ((size_t)(b * 64 + row)) * NN + kt0 + col8);
    }
    __syncthreads();

    // ---- S^T = K Q^T, P packed into registers --------------------------
    s16x4 pk[4][2];
#pragma unroll
    for (int t = 0; t < 4; t++) {
      const bf16x8 kf0 = *(const bf16x8*)(&Kt[(t * 16 + l16) * 72 + quad * 8]);
      const bf16x8 kf1 = *(const bf16x8*)(&Kt[(t * 16 + l16) * 72 + 32 + quad * 8]);
#pragma unroll
      for (int qt = 0; qt < 2; qt++) {
        f32x4 z = (f32x4){0.f, 0.f, 0.f, 0.f};
        z = __builtin_amdgcn_mfma_f32_16x16x32_bf16(kf0, qf[qt][0], z, 0, 0, 0);
        z = __builtin_amdgcn_mfma_f32_16x16x32_bf16(kf1, qf[qt][1], z, 0, 0, 0);
        const float p0 = EXP2(z[0]), p1 = EXP2(z[1]);
        const float p2 = EXP2(z[2]), p3 = EXP2(z[3]);
        l[qt] += (p0 + p1) + (p2 + p3);
        bf16x4 pv;
        pv[0] = (__bf16)p0; pv[1] = (__bf16)p1;
        pv[2] = (__bf16)p2; pv[3] = (__bf16)p3;
        pk[t][qt] = __builtin_bit_cast(s16x4, pv);
      }
    }

    // ---- O^T += V^T P^T : K=16 MFMAs, P straight from registers --------
#pragma unroll
    for (int kg = 0; kg < 4; kg++) {
#pragma unroll
      for (int ct = 0; ct < 4; ct++) {
        const bf16x4 va =
            *(const bf16x4*)(&Vt[(ct * 16 + l16) * 72 + kg * 16 + quad * 4]);
        const s16x4 a = __builtin_bit_cast(s16x4, va);
        acc[0][ct] = __builtin_amdgcn_mfma_f32_16x16x16bf16_1k(
            a, pk[kg][0], acc[0][ct], 0, 0, 0);
        acc[1][ct] = __builtin_amdgcn_mfma_f32_16x16x16bf16_1k(
            a, pk[kg][1], acc[1][ct], 0, 0, 0);
      }
    }
  }

  // ---- epilogue 1: l reduction (2 shuffles per q-tile) ------------------
#pragma unroll
  for (int qt = 0; qt < 2; qt++) {
    float lr = l[qt];
    lr += __shfl_xor(lr, 16);
    lr += __shfl_xor(lr, 32);
    if (quad == 0)
      lpart[((size_t)(s * NB + b)) * NN + q0 + qt * 16 + l16] = lr;
  }

  // ---- epilogue 2: fused proj.  Po^T = Wp * O^T -------------------------
  s16x4 ob[2][4];
#pragma unroll
  for (int qt = 0; qt < 2; qt++)
#pragma unroll
    for (int ch = 0; ch < 4; ch++) {
      bf16x4 t;
#pragma unroll
      for (int r = 0; r < 4; r++) t[r] = (__bf16)acc[qt][ch][r];
      ob[qt][ch] = __builtin_bit_cast(s16x4, t);
    }

#pragma unroll
  for (int cot = 0; cot < 4; cot++) {
    f32x4 po[2];
    po[0] = (f32x4){0.f, 0.f, 0.f, 0.f};
    po[1] = (f32x4){0.f, 0.f, 0.f, 0.f};
#pragma unroll
    for (int ch = 0; ch < 4; ch++) {
      const float4 wv =
          *(const float4*)&wproj[(cot * 16 + l16) * 64 + ch * 16 + quad * 4];
      bf16x4 wb;
      wb[0] = (__bf16)wv.x; wb[1] = (__bf16)wv.y;
      wb[2] = (__bf16)wv.z; wb[3] = (__bf16)wv.w;
      const s16x4 a = __builtin_bit_cast(s16x4, wb);
      po[0] = __builtin_amdgcn_mfma_f32_16x16x16bf16_1k(a, ob[0][ch], po[0], 0, 0, 0);
      po[1] = __builtin_amdgcn_mfma_f32_16x16x16bf16_1k(a, ob[1][ch], po[1], 0, 0, 0);
    }
#pragma unroll
    for (int qt = 0; qt < 2; qt++)
#pragma unroll
      for (int r = 0; r < 4; r++)
        Opart[(((size_t)(s * NB + b)) * 64 + cot * 16 + quad * 4 + r) * NN +
              q0 + qt * 16 + l16] = (__bf16)po[qt][r];
  }
}

// ---------------------------------------------------------------------------
// Kernel 3: slim combine (R14-exact) — sum proj-space split partials, 1/l,
// + bias + residual.  grid(128, B); thread = (c, n-oct), coalesced.
// ---------------------------------------------------------------------------
__global__ __launch_bounds__(256) void combine_kernel(
    const __bf16* __restrict__ Opart, const float* __restrict__ lpart,
    const float* __restrict__ bproj, const float* __restrict__ x,
    float* __restrict__ out)
{
  const int b = blockIdx.y;
  const int n0 = blockIdx.x * 32;
  const int tid = threadIdx.x;

  __shared__ float linv[32];
  if (tid < 32) {
    float lt = 0.f;
#pragma unroll
    for (int s = 0; s < SPLIT; s++)
      lt += lpart[((size_t)(s * NB + b)) * NN + n0 + tid];
    linv[tid] = 1.0f / lt;
  }
  __syncthreads();

  const int c = tid >> 2;
  const int n8 = (tid & 3) * 8;

  float o[8];
#pragma unroll
  for (int j = 0; j < 8; j++) o[j] = 0.f;
#pragma unroll
  for (int s = 0; s < SPLIT; s++) {
    const bf16x8 v = *(const bf16x8*)(
        Opart + (((size_t)(s * NB + b)) * 64 + c) * NN + n0 + n8);
#pragma unroll
    for (int j = 0; j < 8; j++) o[j] += (float)v[j];
  }

  const float bb = bproj[c];
  const float4 li0 = *(const float4*)&linv[n8];
  const float4 li1 = *(const float4*)&linv[n8 + 4];
  const size_t base = ((size_t)(b * 64 + c)) * NN + n0 + n8;
  const float4 x0 = *(const float4*)&x[base];
  const float4 x1 = *(const float4*)&x[base + 4];
  float4 r0, r1;
  r0.x = o[0] * li0.x + bb + x0.x;  r0.y = o[1] * li0.y + bb + x0.y;
  r0.z = o[2] * li0.z + bb + x0.z;  r0.w = o[3] * li0.w + bb + x0.w;
  r1.x = o[4] * li1.x + bb + x1.x;  r1.y = o[5] * li1.y + bb + x1.y;
  r1.z = o[6] * li1.z + bb + x1.z;  r1.w = o[7] * li1.w + bb + x1.w;
  *(float4*)&out[base] = r0;
  *(float4*)&out[base + 4] = r1;
}

extern "C" void kernel_launch(void* const* d_in, const int* in_sizes, int n_in,
                              void* d_out, int out_size, void* d_ws, size_t ws_size,
                              hipStream_t stream) {
  const float* x     = (const float*)d_in[0];
  const float* wqkv  = (const float*)d_in[1];
  const float* bqkv  = (const float*)d_in[2];
  const float* wproj = (const float*)d_in[3];
  const float* bproj = (const float*)d_in[4];
  float* out = (float*)d_out;

  // Workspace: Q[0,2M) K[2,4M) V[4,6M) Opart[6,22M) lpart[23,23.5M)
  char* ws = (char*)d_ws;
  __bf16* Q     = (__bf16*)(ws);
  __bf16* K     = (__bf16*)(ws + (2u << 20));
  __bf16* V     = (__bf16*)(ws + (4u << 20));
  __bf16* Opart = (__bf16*)(ws + (6u << 20));   // [S,B,C,N] = 16 MiB
  float*  lpart = (float*)(ws + (23u << 20));   // SPLIT*B*N*4 = 512 KiB

  qkv_kernel<<<dim3(32, NB, 3), 256, 0, stream>>>(x, wqkv, bqkv, Q, K, V);
  flash_kernel<<<dim3(16, NB, SPLIT), 512, 0, stream>>>(Q, K, V, wproj,
                                                        Opart, lpart);
  combine_kernel<<<dim3(128, NB), 256, 0, stream>>>(Opart, lpart, bproj, x,
                                                    out);
}